// Round 8
// baseline (242.422 us; speedup 1.0000x reference)
//
#include <hip/hip_runtime.h>
#include <hip/hip_bf16.h>
#include <stdint.h>
#include <stddef.h>

using bf16 = __hip_bfloat16;
typedef short short8 __attribute__((ext_vector_type(8)));
typedef short short4v __attribute__((ext_vector_type(4)));
typedef short short2v __attribute__((ext_vector_type(2)));
typedef float f32x4 __attribute__((ext_vector_type(4)));
typedef float f32x16 __attribute__((ext_vector_type(16)));
typedef unsigned uintv4 __attribute__((ext_vector_type(4)));

#define MFMA16(A, B, C) __builtin_amdgcn_mfma_f32_16x16x32_bf16(A, B, C, 0, 0, 0)
#define MFMA32(A, B, C) __builtin_amdgcn_mfma_f32_32x32x16_bf16(A, B, C, 0, 0, 0)
#define GLOAD_LDS(g, l) __builtin_amdgcn_global_load_lds( \
    (const __attribute__((address_space(1))) void*)(g),   \
    (__attribute__((address_space(3))) void*)(l), 16, 0, 0)

// Problem constants
constexpr int AN  = 4096;   // sequence length N
constexpr int NH  = 16;     // heads
constexpr int HD  = 64;     // head dim
constexpr int CC  = 1024;   // channels = NH*HD
constexpr int C3  = 3072;   // 3*CC
// Q pre-scale: D^-0.5 * log2(e)  -> softmax runs in exp2 domain
constexpr float QSCALE = 0.125f * 1.4426950408889634f;

// ---- fast f32 -> bf16 (hardware cvt_pk if present, else bias+perm trick) ----
__device__ inline short bf16s(float f) {
    return (short)((__float_as_uint(f) + 0x8000u) >> 16);
}
__device__ inline float bf2f(short s) {
    return __uint_as_float(((unsigned)(unsigned short)s) << 16);
}
__device__ inline bf16 sbf(short s) {
    union { short s; bf16 b; } u;
    u.s = s;
    return u.b;
}
#if __has_builtin(__builtin_amdgcn_cvt_pk_bf16_f32)
typedef __bf16 bf16x2 __attribute__((ext_vector_type(2)));
__device__ inline short2v pk2(float a, float b) {
    bf16x2 r = __builtin_amdgcn_cvt_pk_bf16_f32(a, b);
    return *(short2v*)&r;
}
#else
__device__ inline short2v pk2(float a, float b) {   // 3 inst
    unsigned ua = __float_as_uint(a) + 0x8000u;
    unsigned ub = __float_as_uint(b) + 0x8000u;
    unsigned r  = __builtin_amdgcn_perm(ub, ua, 0x07060302);
    return *(short2v*)&r;
}
#endif
__device__ inline unsigned pk2u(float a, float b) {
    short2v p = pk2(a, b);
    return *(unsigned*)&p;
}
__device__ inline short4v pack4(float a, float b, float c, float d) {
    short2v lo = pk2(a, b), hi = pk2(c, d);
    short4v r;
    r[0] = lo[0]; r[1] = lo[1]; r[2] = hi[0]; r[3] = hi[1];
    return r;
}
// v_permlane32_swap_b32: upper 32 lanes of %0 exchange with lower 32 lanes
// of %1. After: a = [a_lo | b_lo(from lane-32)], b = [a_hi(from lane+32) | b_hi].
__device__ inline void plswap(unsigned &a, unsigned &b) {
    asm("v_permlane32_swap_b32 %0, %1" : "+v"(a), "+v"(b));
}
#if __has_builtin(__builtin_amdgcn_exp2f)
#define FAST_EXP2(x) __builtin_amdgcn_exp2f(x)
#else
#define FAST_EXP2(x) exp2f(x)
#endif

// ---------------------------------------------------------------------------
// Per-wave dtype detect (no extra kernel): every wave reads the same first
// 256 shorts of x; fp32-read-as-bf16 has ~45% wild exponents.
// ---------------------------------------------------------------------------
__device__ inline int detect_mode_inline(const unsigned short* xraw, int lane) {
    int crazy = 0;
    #pragma unroll
    for (int i = 0; i < 4; ++i) {
        const unsigned short u = xraw[lane * 4 + i];
        const int e = (u >> 7) & 0xFF;
        if (e >= 134 || (e != 0 && e <= 110)) ++crazy;
    }
    #pragma unroll
    for (int off = 32; off > 0; off >>= 1)
        crazy += __shfl_down(crazy, off, 64);
    crazy = __shfl(crazy, 0, 64);   // wave-uniform
    return (crazy >= 8) ? 1 : 0;
}

// ---------------------------------------------------------------------------
// One merged cast kernel: x (2048 blocks) | w_qkv (1536) | w_proj (512) |
// bias+mode (1 block). 8 elements/thread. Mode derived per-wave in-kernel.
// ---------------------------------------------------------------------------
__device__ inline void cast8(const void* __restrict__ src,
                             bf16* __restrict__ dst, int i, int m) {
    if (m) {
        const float* s = (const float*)src;
        float4 a = *(const float4*)(s + i);
        float4 b = *(const float4*)(s + i + 4);
        short8 o;
        short2v p0 = pk2(a.x, a.y), p1 = pk2(a.z, a.w);
        short2v p2 = pk2(b.x, b.y), p3 = pk2(b.z, b.w);
        o[0] = p0[0]; o[1] = p0[1]; o[2] = p1[0]; o[3] = p1[1];
        o[4] = p2[0]; o[5] = p2[1]; o[6] = p3[0]; o[7] = p3[1];
        *(short8*)(dst + i) = o;
    } else {
        *(short8*)(dst + i) = *(const short8*)((const short*)src + i);
    }
}

__global__ void cast_all(const void* __restrict__ x, const void* __restrict__ wq,
                         const void* __restrict__ wp, const void* __restrict__ bp,
                         bf16* __restrict__ xb, bf16* __restrict__ wqb,
                         bf16* __restrict__ wpb, float* __restrict__ biasf,
                         int* __restrict__ mode) {
    const int b = blockIdx.x;
    const int tid = threadIdx.x;
    const int m = detect_mode_inline((const unsigned short*)x, tid & 63);
    if (b < 2048) {
        cast8(x, xb, (b * 256 + tid) * 8, m);
    } else if (b < 3584) {
        cast8(wq, wqb, ((b - 2048) * 256 + tid) * 8, m);
    } else if (b < 4096) {
        cast8(wp, wpb, ((b - 3584) * 256 + tid) * 8, m);
    } else {
        #pragma unroll
        for (int i = tid; i < CC; i += 256)
            biasf[i] = m ? ((const float*)bp)[i] : bf2f(((const short*)bp)[i]);
        if (tid == 0) *mode = m;   // for gemm_proj's output dtype
    }
}

// ---------------------------------------------------------------------------
// QKV GEMM: Q cols scaled by QSCALE into qbuf[n][CC]; K cols written to
// fragment-major kPack[h][kvtile][dchunk(8)][row(64)][8]; V cols written to
// fragment-major vPack[h][kvtile][kvchunk(8)][d(64)][8].
// K blocks use SWAPPED MFMA operands so each lane's output fragment holds 4
// consecutive d at one kv row -> K epilogue is 16 packed 8B stores (was 64
// scalar 2B stores; ~8us of "others" recovered).
// 128x128 tile, BK=32, grid 24x32 = 768 = 3 blocks/CU exact fill.
// ---------------------------------------------------------------------------
constexpr int BM = 128, BN = 128, BK = 32;

__global__ __launch_bounds__(256, 3) void gemm_qkv(
    const bf16* __restrict__ A, const bf16* __restrict__ Bw,
    bf16* __restrict__ qOut, bf16* __restrict__ kOut, bf16* __restrict__ vOut)
{
    __shared__ bf16 As[BM * BK];
    __shared__ bf16 Bs[BN * BK];

    const int tid  = threadIdx.x;
    const int wave = tid >> 6;
    const int lane = tid & 63;
    const int quad = lane >> 4;
    const int l16  = lane & 15;
    const int wr   = wave >> 1;
    const int wc   = wave & 1;
    const int m0   = blockIdx.y * BM;
    const int o0   = blockIdx.x * BN;
    const bool isK = (o0 >= CC) && (o0 < 2 * CC);

    const int srow = lane >> 2;
    const int scol = (lane & 3) * 8;

    f32x4 acc[4][4] = {};

    for (int k0 = 0; k0 < CC; k0 += BK) {
        __syncthreads();
        #pragma unroll
        for (int c = 0; c < 2; ++c) {
            const int rbase = wave * 32 + c * 16;
            GLOAD_LDS(A + (size_t)(m0 + rbase + srow) * CC + k0 + scol, &As[rbase * BK]);
            GLOAD_LDS(Bw + (size_t)(o0 + rbase + srow) * CC + k0 + scol, &Bs[rbase * BK]);
        }
        __syncthreads();

        short8 af[4], bfr[4];
        #pragma unroll
        for (int i = 0; i < 4; ++i)
            af[i] = *(const short8*)&As[(wr * 64 + i * 16 + l16) * BK + quad * 8];
        #pragma unroll
        for (int j = 0; j < 4; ++j)
            bfr[j] = *(const short8*)&Bs[(wc * 64 + j * 16 + l16) * BK + quad * 8];
        if (isK) {   // swapped operands: output fragment transposed
            #pragma unroll
            for (int i = 0; i < 4; ++i)
                #pragma unroll
                for (int j = 0; j < 4; ++j)
                    acc[i][j] = MFMA16(bfr[j], af[i], acc[i][j]);
        } else {
            #pragma unroll
            for (int i = 0; i < 4; ++i)
                #pragma unroll
                for (int j = 0; j < 4; ++j)
                    acc[i][j] = MFMA16(af[i], bfr[j], acc[i][j]);
        }
    }

    if (o0 >= 2 * CC) {   // V block -> vPack[h][tile][kvchunk][d][8]
        // epilogue (normal orientation): col=l16 (d), row=quad*4+reg (kv)
        #pragma unroll
        for (int j = 0; j < 4; ++j) {
            const int dcol = o0 - 2 * CC + wc * 64 + j * 16 + l16;
            const int hV = dcol >> 6, dV = dcol & 63;
            #pragma unroll
            for (int i = 0; i < 4; ++i) {
                const int kv0 = m0 + wr * 64 + i * 16 + quad * 4;
                const size_t addr = (size_t)hV * 64 * AN + (size_t)(kv0 >> 6) * 4096
                                  + (size_t)((kv0 >> 3) & 7) * 512 + dV * 8 + (kv0 & 7);
                *(short4v*)&vOut[addr] =
                    pack4(acc[i][j][0], acc[i][j][1], acc[i][j][2], acc[i][j][3]);
            }
        }
        return;
    }
    if (isK) {            // K block, swapped: col=l16 (kv), row=quad*4+reg (d)
        #pragma unroll
        for (int i = 0; i < 4; ++i) {
            const int kv = m0 + wr * 64 + i * 16 + l16;
            const size_t rowoff = (size_t)(kv >> 6) * 4096 + (size_t)(kv & 63) * 8;
            #pragma unroll
            for (int j = 0; j < 4; ++j) {
                const int d0 = (o0 - CC) + wc * 64 + j * 16 + quad * 4;
                const int hK = d0 >> 6, dc = (d0 >> 3) & 7, de = d0 & 7;
                const size_t addr = (size_t)hK * 64 * AN + rowoff
                                  + (size_t)dc * 512 + de;
                *(short4v*)&kOut[addr] =
                    pack4(acc[i][j][0], acc[i][j][1], acc[i][j][2], acc[i][j][3]);
            }
        }
        return;
    }
    // Q block -> qbuf[n][CC], scaled
    #pragma unroll
    for (int j = 0; j < 4; ++j) {
        const int col = o0 + wc * 64 + j * 16 + l16;
        #pragma unroll
        for (int i = 0; i < 4; ++i) {
            const int row = m0 + wr * 64 + i * 16 + quad * 4;
            #pragma unroll
            for (int r = 0; r < 2; ++r) {
                short2v p = pk2(acc[i][j][2 * r] * QSCALE, acc[i][j][2 * r + 1] * QSCALE);
                qOut[(size_t)(row + 2 * r) * CC + col]     = sbf(p[0]);
                qOut[(size_t)(row + 2 * r + 1) * CC + col] = sbf(p[1]);
            }
        }
    }
}

// ---------------------------------------------------------------------------
// Proj GEMM: out[m][o] = sum_c attn[m][c]*wp[o][c] + bias[o].
// 128x64 tile -> grid 16x32 = 512 = 2 blocks/CU exact fill.
// ---------------------------------------------------------------------------
constexpr int PM = 128, PN = 64, PK = 32;

__global__ __launch_bounds__(256, 2) void gemm_proj(
    const bf16* __restrict__ A, const bf16* __restrict__ Bw,
    const float* __restrict__ bias, void* __restrict__ Cout,
    const int* __restrict__ mode)
{
    __shared__ bf16 As[PM * PK];   // 8 KB
    __shared__ bf16 Bs[PN * PK];   // 4 KB

    const int tid  = threadIdx.x;
    const int wave = tid >> 6;
    const int lane = tid & 63;
    const int quad = lane >> 4;
    const int l16  = lane & 15;
    const int wr   = wave >> 1;
    const int wc   = wave & 1;
    const int m0   = blockIdx.y * PM;
    const int o0   = blockIdx.x * PN;
    const bool f32out = (*mode != 0);

    const int srow = lane >> 2;
    const int scol = (lane & 3) * 8;

    f32x4 acc[4][2] = {};

    for (int k0 = 0; k0 < CC; k0 += PK) {
        __syncthreads();
        #pragma unroll
        for (int c = 0; c < 2; ++c) {
            const int rbase = wave * 32 + c * 16;
            GLOAD_LDS(A + (size_t)(m0 + rbase + srow) * CC + k0 + scol, &As[rbase * PK]);
        }
        {
            const int rbase = wave * 16;
            GLOAD_LDS(Bw + (size_t)(o0 + rbase + srow) * CC + k0 + scol, &Bs[rbase * PK]);
        }
        __syncthreads();

        short8 af[4], bfr[2];
        #pragma unroll
        for (int i = 0; i < 4; ++i)
            af[i] = *(const short8*)&As[(wr * 64 + i * 16 + l16) * PK + quad * 8];
        #pragma unroll
        for (int j = 0; j < 2; ++j)
            bfr[j] = *(const short8*)&Bs[(wc * 32 + j * 16 + l16) * PK + quad * 8];
        #pragma unroll
        for (int i = 0; i < 4; ++i)
            #pragma unroll
            for (int j = 0; j < 2; ++j)
                acc[i][j] = MFMA16(af[i], bfr[j], acc[i][j]);
    }

    #pragma unroll
    for (int j = 0; j < 2; ++j) {
        const int col = o0 + wc * 32 + j * 16 + l16;
        const float bv = bias[col];
        #pragma unroll
        for (int i = 0; i < 4; ++i) {
            const int row = m0 + wr * 64 + i * 16 + quad * 4;
            if (f32out) {
                #pragma unroll
                for (int r = 0; r < 4; ++r)
                    ((float*)Cout)[(size_t)(row + r) * CC + col] = acc[i][j][r] + bv;
            } else {
                #pragma unroll
                for (int r = 0; r < 2; ++r) {
                    short2v p = pk2(acc[i][j][2 * r] + bv, acc[i][j][2 * r + 1] + bv);
                    ((bf16*)Cout)[(size_t)(row + 2 * r) * CC + col]     = sbf(p[0]);
                    ((bf16*)Cout)[(size_t)(row + 2 * r + 1) * CC + col] = sbf(p[1]);
                }
            }
        }
    }
}

// ---------------------------------------------------------------------------
// Causal flash attention v13: 64 q-rows per wave, 32-kv steps — every loaded
// K/V fragment feeds TWO 32-row q groups (arithmetic intensity per load 2x
// attn8; loads/iter 16KB -> 8KB; MFMA+VALU per iter unchanged).
//  - block = (h,t), 2 waves = kv sub-split s; pairing (t,63-t) via pp loop:
//    q-tile tau gets steps [0,tau+1) from block tau pp0, [tau+1, 2tau+2)
//    from block 63-tau pp1; each phase split between the 2 s waves -> every
//    block runs exactly 65 steps total, waves ~32.5.
//  - per step j: triG0 (j==2*tile): group0 triangular; j==2*tile+1: group0
//    skipped + group1 triangular.
//  - no LDS, no barriers; reg-direct frag loads; K prefetched 1 step ahead
//    (after both groups' S); V loaded at step top (PV slack).
//  - 4 partial slots (pp*2+s), combine4 unchanged.
// VGPR est ~200 (<256 cap of (128,2)); spill tripwire = FETCH_SIZE.
// ---------------------------------------------------------------------------
__global__ __launch_bounds__(128, 2) void attn13(
    const bf16* __restrict__ qbuf, const bf16* __restrict__ kP,
    const bf16* __restrict__ vP, bf16* __restrict__ pOn, float* __restrict__ pl)
{
    const int tid  = threadIdx.x;
    const int s    = tid >> 6;        // wave id = kv sub-split
    const int lane = tid & 63;
    const int l31  = lane & 31;
    const int hh   = lane >> 5;       // K-half of the 32x32x16 fragment
    const int bid  = blockIdx.x;
    const int h    = bid & 15;
    const int t    = bid >> 4;        // 0..63

    short8 ones8;
    #pragma unroll
    for (int i = 0; i < 8; ++i) ones8[i] = (short)0x3F80;

    #pragma unroll 1
    for (int pp = 0; pp < 2; ++pp) {
        const int tile = pp ? 63 - t : t;
        const int lo   = pp ? tile + 1 : 0;          // phase step range
        const int hi   = pp ? 2 * tile + 2 : tile + 1;
        const int mid  = lo + ((hi - lo + 1) >> 1);
        const int i0   = s ? mid : lo;
        const int iHi  = s ? hi : mid;
        const int slot = pp * 2 + s;
        const int qb   = tile * 64;
        const int q0   = qb + l31;        // group 0 q col
        const int q1   = qb + 32 + l31;   // group 1 q col

        // Q fragments, both groups: B-operand Q[k=hd][col=q]
        short8 qf[2][4];
        #pragma unroll
        for (int g = 0; g < 2; ++g) {
            const bf16* qp = qbuf + (size_t)(qb + 32 * g + l31) * CC + h * HD + hh * 8;
            #pragma unroll
            for (int ki = 0; ki < 4; ++ki)
                qf[g][ki] = *(const short8*)(qp + ki * 16);
        }

        f32x16 acc_l[2] = {};
        f32x16 acc_o[2][2] = {};   // [group][dt2]

        if (i0 < iHi) {
            const bf16* kb = kP + (size_t)h * 64 * AN;
            const bf16* vb = vP + (size_t)h * 64 * AN;

            // softmax (+optional causal mask) then pack to PV B-frags
            auto smpack = [&](f32x16 &st, int qv, bool tri, int kvb, short8 (&fr)[2]) {
                if (tri) {
                    #pragma unroll
                    for (int r = 0; r < 16; ++r) {
                        const int kv = kvb + (r & 3) + 8 * (r >> 2) + 4 * hh;
                        st[r] = (kv <= qv) ? FAST_EXP2(st[r]) : 0.0f;
                    }
                } else {
                    #pragma unroll
                    for (int r = 0; r < 16; ++r)
                        st[r] = FAST_EXP2(st[r]);
                }
                #pragma unroll
                for (int kc = 0; kc < 2; ++kc) {
                    unsigned a0 = pk2u(st[kc * 8 + 0], st[kc * 8 + 1]);
                    unsigned a1 = pk2u(st[kc * 8 + 2], st[kc * 8 + 3]);
                    unsigned c0 = pk2u(st[kc * 8 + 4], st[kc * 8 + 5]);
                    unsigned c1 = pk2u(st[kc * 8 + 6], st[kc * 8 + 7]);
                    plswap(a0, c0);
                    plswap(a1, c1);
                    uintv4 fu;
                    fu[0] = a0; fu[1] = a1; fu[2] = c0; fu[3] = c1;
                    fr[kc] = *(const short8*)&fu;
                }
            };

            // prologue: K(i0) direct to registers
            short8 kf[4];
            #pragma unroll
            for (int ki = 0; ki < 4; ++ki)
                kf[ki] = *(const short8*)(kb + (size_t)(i0 >> 1) * 4096
                          + (i0 & 1) * 256 + (2 * ki + hh) * 512 + l31 * 8);

            for (int j = i0; j < iHi; ++j) {
                const bool triG0  = (j == 2 * tile);
                const bool skipG0 = (j == 2 * tile + 1);   // also: triG1
                const int  kvb    = j * 32;

                // ---- V loads for this step (consumed in PV) ----
                short8 vf[2][2];
                {
                    const bf16* vs = vb + (size_t)(j >> 1) * 4096 + (j & 1) * 2048;
                    #pragma unroll
                    for (int kc = 0; kc < 2; ++kc)
                        #pragma unroll
                        for (int dt2 = 0; dt2 < 2; ++dt2)
                            vf[kc][dt2] = *(const short8*)
                                (vs + (2 * kc + hh) * 512 + (dt2 * 32 + l31) * 8);
                }

                short8 fr0[2], fr1[2];

                // ---- group 0: S, softmax, pack (skipped on step 2*tile+1) ----
                if (!skipG0) {
                    f32x16 st = {};
                    __builtin_amdgcn_s_setprio(1);
                    #pragma unroll
                    for (int ki = 0; ki < 4; ++ki)
                        st = MFMA32(kf[ki], qf[0][ki], st);
                    __builtin_amdgcn_s_setprio(0);
                    smpack(st, q0, triG0, kvb, fr0);
                }

                // ---- group 1: S (reuses kf!) ----
                f32x16 st1 = {};
                __builtin_amdgcn_s_setprio(1);
                #pragma unroll
                for (int ki = 0; ki < 4; ++ki)
                    st1 = MFMA32(kf[ki], qf[1][ki], st1);
                __builtin_amdgcn_s_setprio(0);

                // ---- K prefetch for step j+1 (kf dead after S g1) ----
                if (j + 1 < iHi) {
                    #pragma unroll
                    for (int ki = 0; ki < 4; ++ki)
                        kf[ki] = *(const short8*)(kb + (size_t)((j + 1) >> 1) * 4096
                                  + ((j + 1) & 1) * 256 + (2 * ki + hh) * 512 + l31 * 8);
                }

                // ---- group 1 softmax + pack (tri on step 2*tile+1) ----
                smpack(st1, q1, skipG0, kvb, fr1);

                // ---- PV + lsum, both groups ----
                __builtin_amdgcn_s_setprio(1);
                if (!skipG0) {
                    #pragma unroll
                    for (int kc = 0; kc < 2; ++kc) {
                        acc_l[0] = MFMA32(ones8, fr0[kc], acc_l[0]);
                        #pragma unroll
                        for (int dt2 = 0; dt2 < 2; ++dt2)
                            acc_o[0][dt2] = MFMA32(vf[kc][dt2], fr0[kc], acc_o[0][dt2]);
                    }
                }
                #pragma unroll
                for (int kc = 0; kc < 2; ++kc) {
                    acc_l[1] = MFMA32(ones8, fr1[kc], acc_l[1]);
                    #pragma unroll
                    for (int dt2 = 0; dt2 < 2; ++dt2)
                        acc_o[1][dt2] = MFMA32(vf[kc][dt2], fr1[kc], acc_o[1][dt2]);
                }
                __builtin_amdgcn_s_setprio(0);
            }
        }

        // ---- epilogue: unnormalized partial O (bf16) + l, both groups ----
        #pragma unroll
        for (int g = 0; g < 2; ++g) {
            const size_t base = (size_t)slot * AN * CC
                              + (size_t)(qb + 32 * g + l31) * CC + h * HD;
            #pragma unroll
            for (int dt2 = 0; dt2 < 2; ++dt2)
                #pragma unroll
                for (int gi = 0; gi < 4; ++gi) {
                    const int d0 = dt2 * 32 + gi * 8 + 4 * hh;
                    *(short4v*)&pOn[base + d0] =
                        pack4(acc_o[g][dt2][4 * gi + 0], acc_o[g][dt2][4 * gi + 1],
                              acc_o[g][dt2][4 * gi + 2], acc_o[g][dt2][4 * gi + 3]);
                }
            if (hh == 0)
                pl[(size_t)slot * NH * AN + (size_t)h * AN + qb + 32 * g + l31] =
                    acc_l[g][0];
        }
    }
}

// ---------------------------------------------------------------------------
// Combine the four KV partials: out = (O0+O1+O2+O3) / (l0+l1+l2+l3).
// ---------------------------------------------------------------------------
__global__ __launch_bounds__(128) void combine4(
    const bf16* __restrict__ pOn, const float* __restrict__ pl,
    bf16* __restrict__ outp)
{
    const int q  = blockIdx.x;
    const int c0 = threadIdx.x * 8;
    const int h  = c0 >> 6;
    float L = 0.f;
    #pragma unroll
    for (int k = 0; k < 4; ++k)
        L += pl[(size_t)k * NH * AN + (size_t)h * AN + q];
    const float invL = (L > 0.f) ? 1.f / L : 0.f;
    const size_t off = (size_t)q * CC + c0;
    float acc[8] = {};
    #pragma unroll
    for (int k = 0; k < 4; ++k) {
        short8 ov = *(const short8*)&pOn[(size_t)k * AN * CC + off];
        #pragma unroll
        for (int e = 0; e < 8; ++e)
            acc[e] += bf2f(ov[e]);
    }
    short8 o;
    #pragma unroll
    for (int e = 0; e < 8; e += 2) {
        short2v p = pk2(acc[e] * invL, acc[e + 1] * invL);
        o[e] = p[0]; o[e + 1] = p[1];
    }
    *(short8*)&outp[off] = o;
}

// ---------------------------------------------------------------------------
extern "C" void kernel_launch(void* const* d_in, const int* in_sizes, int n_in,
                              void* d_out, int out_size, void* d_ws, size_t ws_size,
                              hipStream_t stream) {
    char* ws = (char*)d_ws;
    bf16*   qbuf     = (bf16*)(ws);                    //  8 MiB [4096][1024]
    bf16*   kPack    = (bf16*)(ws + 8388608);          //  8 MiB frag-major K
    bf16*   vPack    = (bf16*)(ws + 16777216);         //  8 MiB frag-major V
    bf16*   attn_out = (bf16*)(ws + 25165824);         //  8 MiB [4096][1024]
    bf16*   wprojb   = (bf16*)(ws + 33554432);         //  2 MiB
    float*  biasf    = (float*)(ws + 35651584);        //  4 KiB
    int*    mode     = (int*)(ws + 35655680);
    float*  pl       = (float*)(ws + 35659776);        //  1 MiB [4][16][4096]
    bf16*   xb       = (bf16*)(ws + 36708352);         //  8 MiB (dead after qkv)
    bf16*   wqkvb    = (bf16*)(ws + 45096960);         //  6 MiB (dead after qkv)
    // pOn overlays xb+wqkvb (both dead once attn runs): 32 MiB [4][4096][1024]
    bf16*   pOn      = (bf16*)(ws + 36708352);

    cast_all<<<dim3(4097), 256, 0, stream>>>(
        d_in[0], d_in[1], d_in[2], d_in[3], xb, wqkvb, wprojb, biasf, mode);

    // QKV projection: Q scaled -> qbuf; K -> kPack (swapped-op epilogue);
    // V -> vPack (frag-major)
    gemm_qkv<<<dim3(C3 / BN, AN / BM), 256, 0, stream>>>(
        xb, wqkvb, qbuf, kPack, vPack);
    // causal flash attention: 64 q/wave, 32-kv steps, 2x reuse per load
    attn13<<<dim3(64 * NH), 128, 0, stream>>>(qbuf, kPack, vPack, pOn, pl);
    // merge the four partials
    combine4<<<dim3(AN), 128, 0, stream>>>(pOn, pl, attn_out);
    // output projection + bias
    gemm_proj<<<dim3(CC / PN, AN / PM), 256, 0, stream>>>(
        attn_out, wprojb, biasf, d_out, mode);
}

// Round 9
// 186.124 us; speedup vs baseline: 1.3025x; 1.3025x over previous
//
#include <hip/hip_runtime.h>
#include <hip/hip_bf16.h>
#include <stdint.h>
#include <stddef.h>

using bf16 = __hip_bfloat16;
typedef short short8 __attribute__((ext_vector_type(8)));
typedef short short4v __attribute__((ext_vector_type(4)));
typedef short short2v __attribute__((ext_vector_type(2)));
typedef float f32x4 __attribute__((ext_vector_type(4)));
typedef float f32x16 __attribute__((ext_vector_type(16)));
typedef unsigned uintv4 __attribute__((ext_vector_type(4)));

#define MFMA16(A, B, C) __builtin_amdgcn_mfma_f32_16x16x32_bf16(A, B, C, 0, 0, 0)
#define MFMA32(A, B, C) __builtin_amdgcn_mfma_f32_32x32x16_bf16(A, B, C, 0, 0, 0)
#define GLOAD_LDS(g, l) __builtin_amdgcn_global_load_lds( \
    (const __attribute__((address_space(1))) void*)(g),   \
    (__attribute__((address_space(3))) void*)(l), 16, 0, 0)

// Problem constants
constexpr int AN  = 4096;   // sequence length N
constexpr int NH  = 16;     // heads
constexpr int HD  = 64;     // head dim
constexpr int CC  = 1024;   // channels = NH*HD
constexpr int C3  = 3072;   // 3*CC
// Q pre-scale: D^-0.5 * log2(e)  -> softmax runs in exp2 domain
constexpr float QSCALE = 0.125f * 1.4426950408889634f;

// ---- fast f32 -> bf16 (hardware cvt_pk if present, else bias+perm trick) ----
__device__ inline short bf16s(float f) {
    return (short)((__float_as_uint(f) + 0x8000u) >> 16);
}
__device__ inline float bf2f(short s) {
    return __uint_as_float(((unsigned)(unsigned short)s) << 16);
}
__device__ inline bf16 sbf(short s) {
    union { short s; bf16 b; } u;
    u.s = s;
    return u.b;
}
#if __has_builtin(__builtin_amdgcn_cvt_pk_bf16_f32)
typedef __bf16 bf16x2 __attribute__((ext_vector_type(2)));
__device__ inline short2v pk2(float a, float b) {
    bf16x2 r = __builtin_amdgcn_cvt_pk_bf16_f32(a, b);
    return *(short2v*)&r;
}
#else
__device__ inline short2v pk2(float a, float b) {   // 3 inst
    unsigned ua = __float_as_uint(a) + 0x8000u;
    unsigned ub = __float_as_uint(b) + 0x8000u;
    unsigned r  = __builtin_amdgcn_perm(ub, ua, 0x07060302);
    return *(short2v*)&r;
}
#endif
__device__ inline unsigned pk2u(float a, float b) {
    short2v p = pk2(a, b);
    return *(unsigned*)&p;
}
__device__ inline short4v pack4(float a, float b, float c, float d) {
    short2v lo = pk2(a, b), hi = pk2(c, d);
    short4v r;
    r[0] = lo[0]; r[1] = lo[1]; r[2] = hi[0]; r[3] = hi[1];
    return r;
}
// v_permlane32_swap_b32: upper 32 lanes of %0 exchange with lower 32 lanes
// of %1. After: a = [a_lo | b_lo(from lane-32)], b = [a_hi(from lane+32) | b_hi].
__device__ inline void plswap(unsigned &a, unsigned &b) {
    asm("v_permlane32_swap_b32 %0, %1" : "+v"(a), "+v"(b));
}
#if __has_builtin(__builtin_amdgcn_exp2f)
#define FAST_EXP2(x) __builtin_amdgcn_exp2f(x)
#else
#define FAST_EXP2(x) exp2f(x)
#endif

// ---------------------------------------------------------------------------
// Per-wave dtype detect (no extra kernel): every wave reads the same first
// 256 shorts of x; fp32-read-as-bf16 has ~45% wild exponents.
// ---------------------------------------------------------------------------
__device__ inline int detect_mode_inline(const unsigned short* xraw, int lane) {
    int crazy = 0;
    #pragma unroll
    for (int i = 0; i < 4; ++i) {
        const unsigned short u = xraw[lane * 4 + i];
        const int e = (u >> 7) & 0xFF;
        if (e >= 134 || (e != 0 && e <= 110)) ++crazy;
    }
    #pragma unroll
    for (int off = 32; off > 0; off >>= 1)
        crazy += __shfl_down(crazy, off, 64);
    crazy = __shfl(crazy, 0, 64);   // wave-uniform
    return (crazy >= 8) ? 1 : 0;
}

// ---------------------------------------------------------------------------
// One merged cast kernel: x (2048 blocks) | w_qkv (1536) | w_proj (512) |
// bias+mode (1 block). 8 elements/thread. Mode derived per-wave in-kernel.
// ---------------------------------------------------------------------------
__device__ inline void cast8(const void* __restrict__ src,
                             bf16* __restrict__ dst, int i, int m) {
    if (m) {
        const float* s = (const float*)src;
        float4 a = *(const float4*)(s + i);
        float4 b = *(const float4*)(s + i + 4);
        short8 o;
        short2v p0 = pk2(a.x, a.y), p1 = pk2(a.z, a.w);
        short2v p2 = pk2(b.x, b.y), p3 = pk2(b.z, b.w);
        o[0] = p0[0]; o[1] = p0[1]; o[2] = p1[0]; o[3] = p1[1];
        o[4] = p2[0]; o[5] = p2[1]; o[6] = p3[0]; o[7] = p3[1];
        *(short8*)(dst + i) = o;
    } else {
        *(short8*)(dst + i) = *(const short8*)((const short*)src + i);
    }
}

__global__ void cast_all(const void* __restrict__ x, const void* __restrict__ wq,
                         const void* __restrict__ wp, const void* __restrict__ bp,
                         bf16* __restrict__ xb, bf16* __restrict__ wqb,
                         bf16* __restrict__ wpb, float* __restrict__ biasf,
                         int* __restrict__ mode) {
    const int b = blockIdx.x;
    const int tid = threadIdx.x;
    const int m = detect_mode_inline((const unsigned short*)x, tid & 63);
    if (b < 2048) {
        cast8(x, xb, (b * 256 + tid) * 8, m);
    } else if (b < 3584) {
        cast8(wq, wqb, ((b - 2048) * 256 + tid) * 8, m);
    } else if (b < 4096) {
        cast8(wp, wpb, ((b - 3584) * 256 + tid) * 8, m);
    } else {
        #pragma unroll
        for (int i = tid; i < CC; i += 256)
            biasf[i] = m ? ((const float*)bp)[i] : bf2f(((const short*)bp)[i]);
        if (tid == 0) *mode = m;   // for gemm_proj's output dtype
    }
}

// ---------------------------------------------------------------------------
// QKV GEMM: Q cols scaled by QSCALE into qbuf[n][CC]; K cols written to
// fragment-major kPack[h][kvtile][dchunk(8)][row(64)][8]; V cols written to
// fragment-major vPack[h][kvtile][kvchunk(8)][d(64)][8].
// [Round-8 lesson: the swapped-operand K epilogue pushed gemm_qkv to 88 us
//  HBM-bound (WRITE 188 MB). Reverted verbatim to the round-5 version.]
// 128x128 tile, BK=32, grid 24x32 = 768 = 3 blocks/CU exact fill.
// ---------------------------------------------------------------------------
constexpr int BM = 128, BN = 128, BK = 32;

__global__ __launch_bounds__(256, 3) void gemm_qkv(
    const bf16* __restrict__ A, const bf16* __restrict__ Bw,
    bf16* __restrict__ qOut, bf16* __restrict__ kOut, bf16* __restrict__ vOut)
{
    __shared__ bf16 As[BM * BK];
    __shared__ bf16 Bs[BN * BK];

    const int tid  = threadIdx.x;
    const int wave = tid >> 6;
    const int lane = tid & 63;
    const int quad = lane >> 4;
    const int l16  = lane & 15;
    const int wr   = wave >> 1;
    const int wc   = wave & 1;
    const int m0   = blockIdx.y * BM;
    const int o0   = blockIdx.x * BN;

    const int srow = lane >> 2;
    const int scol = (lane & 3) * 8;

    f32x4 acc[4][4] = {};

    for (int k0 = 0; k0 < CC; k0 += BK) {
        __syncthreads();
        #pragma unroll
        for (int c = 0; c < 2; ++c) {
            const int rbase = wave * 32 + c * 16;
            GLOAD_LDS(A + (size_t)(m0 + rbase + srow) * CC + k0 + scol, &As[rbase * BK]);
            GLOAD_LDS(Bw + (size_t)(o0 + rbase + srow) * CC + k0 + scol, &Bs[rbase * BK]);
        }
        __syncthreads();

        short8 af[4], bfr[4];
        #pragma unroll
        for (int i = 0; i < 4; ++i)
            af[i] = *(const short8*)&As[(wr * 64 + i * 16 + l16) * BK + quad * 8];
        #pragma unroll
        for (int j = 0; j < 4; ++j)
            bfr[j] = *(const short8*)&Bs[(wc * 64 + j * 16 + l16) * BK + quad * 8];
        #pragma unroll
        for (int i = 0; i < 4; ++i)
            #pragma unroll
            for (int j = 0; j < 4; ++j)
                acc[i][j] = MFMA16(af[i], bfr[j], acc[i][j]);
    }

    // epilogue: C/D layout col=l16, row=quad*4+reg
    if (o0 >= 2 * CC) {   // V block -> vPack[h][tile][kvchunk][d][8]
        #pragma unroll
        for (int j = 0; j < 4; ++j) {
            const int dcol = o0 - 2 * CC + wc * 64 + j * 16 + l16;
            const int hV = dcol >> 6, dV = dcol & 63;
            #pragma unroll
            for (int i = 0; i < 4; ++i) {
                const int kv0 = m0 + wr * 64 + i * 16 + quad * 4;
                const size_t addr = (size_t)hV * 64 * AN + (size_t)(kv0 >> 6) * 4096
                                  + (size_t)((kv0 >> 3) & 7) * 512 + dV * 8 + (kv0 & 7);
                *(short4v*)&vOut[addr] =
                    pack4(acc[i][j][0], acc[i][j][1], acc[i][j][2], acc[i][j][3]);
            }
        }
        return;
    }
    if (o0 >= CC) {       // K block -> kPack[h][tile][dchunk][row][8]
        #pragma unroll
        for (int j = 0; j < 4; ++j) {
            const int dcol = o0 - CC + wc * 64 + j * 16 + l16;
            const int hK = dcol >> 6, dc = (dcol >> 3) & 7, de = dcol & 7;
            #pragma unroll
            for (int i = 0; i < 4; ++i) {
                const int kv0 = m0 + wr * 64 + i * 16 + quad * 4;
                const size_t addr = (size_t)hK * 64 * AN + (size_t)(kv0 >> 6) * 4096
                                  + (size_t)dc * 512 + (size_t)(kv0 & 63) * 8 + de;
                #pragma unroll
                for (int r = 0; r < 4; ++r)
                    kOut[addr + r * 8] = sbf(bf16s(acc[i][j][r]));
            }
        }
        return;
    }
    // Q block -> qbuf[n][CC], scaled
    #pragma unroll
    for (int j = 0; j < 4; ++j) {
        const int col = o0 + wc * 64 + j * 16 + l16;
        #pragma unroll
        for (int i = 0; i < 4; ++i) {
            const int row = m0 + wr * 64 + i * 16 + quad * 4;
            #pragma unroll
            for (int r = 0; r < 2; ++r) {
                short2v p = pk2(acc[i][j][2 * r] * QSCALE, acc[i][j][2 * r + 1] * QSCALE);
                qOut[(size_t)(row + 2 * r) * CC + col]     = sbf(p[0]);
                qOut[(size_t)(row + 2 * r + 1) * CC + col] = sbf(p[1]);
            }
        }
    }
}

// ---------------------------------------------------------------------------
// Proj GEMM: out[m][o] = sum_c attn[m][c]*wp[o][c] + bias[o].
// 128x64 tile -> grid 16x32 = 512 = 2 blocks/CU exact fill.
// ---------------------------------------------------------------------------
constexpr int PM = 128, PN = 64, PK = 32;

__global__ __launch_bounds__(256, 2) void gemm_proj(
    const bf16* __restrict__ A, const bf16* __restrict__ Bw,
    const float* __restrict__ bias, void* __restrict__ Cout,
    const int* __restrict__ mode)
{
    __shared__ bf16 As[PM * PK];   // 8 KB
    __shared__ bf16 Bs[PN * PK];   // 4 KB

    const int tid  = threadIdx.x;
    const int wave = tid >> 6;
    const int lane = tid & 63;
    const int quad = lane >> 4;
    const int l16  = lane & 15;
    const int wr   = wave >> 1;
    const int wc   = wave & 1;
    const int m0   = blockIdx.y * PM;
    const int o0   = blockIdx.x * PN;
    const bool f32out = (*mode != 0);

    const int srow = lane >> 2;
    const int scol = (lane & 3) * 8;

    f32x4 acc[4][2] = {};

    for (int k0 = 0; k0 < CC; k0 += PK) {
        __syncthreads();
        #pragma unroll
        for (int c = 0; c < 2; ++c) {
            const int rbase = wave * 32 + c * 16;
            GLOAD_LDS(A + (size_t)(m0 + rbase + srow) * CC + k0 + scol, &As[rbase * PK]);
        }
        {
            const int rbase = wave * 16;
            GLOAD_LDS(Bw + (size_t)(o0 + rbase + srow) * CC + k0 + scol, &Bs[rbase * PK]);
        }
        __syncthreads();

        short8 af[4], bfr[2];
        #pragma unroll
        for (int i = 0; i < 4; ++i)
            af[i] = *(const short8*)&As[(wr * 64 + i * 16 + l16) * PK + quad * 8];
        #pragma unroll
        for (int j = 0; j < 2; ++j)
            bfr[j] = *(const short8*)&Bs[(wc * 32 + j * 16 + l16) * PK + quad * 8];
        #pragma unroll
        for (int i = 0; i < 4; ++i)
            #pragma unroll
            for (int j = 0; j < 2; ++j)
                acc[i][j] = MFMA16(af[i], bfr[j], acc[i][j]);
    }

    #pragma unroll
    for (int j = 0; j < 2; ++j) {
        const int col = o0 + wc * 32 + j * 16 + l16;
        const float bv = bias[col];
        #pragma unroll
        for (int i = 0; i < 4; ++i) {
            const int row = m0 + wr * 64 + i * 16 + quad * 4;
            if (f32out) {
                #pragma unroll
                for (int r = 0; r < 4; ++r)
                    ((float*)Cout)[(size_t)(row + r) * CC + col] = acc[i][j][r] + bv;
            } else {
                #pragma unroll
                for (int r = 0; r < 2; ++r) {
                    short2v p = pk2(acc[i][j][2 * r] + bv, acc[i][j][2 * r + 1] + bv);
                    ((bf16*)Cout)[(size_t)(row + 2 * r) * CC + col]     = sbf(p[0]);
                    ((bf16*)Cout)[(size_t)(row + 2 * r + 1) * CC + col] = sbf(p[1]);
                }
            }
        }
    }
}

// ---------------------------------------------------------------------------
// Causal flash attention v14: attn8's wave program (best measured, 57.6 us)
// with IN-BLOCK kv-split combine — no pOn partials, no combine kernel.
//  - 512 blocks = (h, bp in 0..31), 4 waves = (rowhalf rh, kv-half s).
//  - pp phase 0: tile bp; phase 1: tile 63-bp. Per phase, wave (rh,s) runs
//    kv-half s of that tile's [0, nIt) steps; per wave total = ceil(nIt/2)
//    + ceil(nIt'/2) ~= 33 iters, uniform +-1 across all blocks.
//  - After each phase: s=1 waves park acc_o/acc_l in LDS (16.5 KB), one
//    barrier, s=0 waves add partner partials, normalize by 1/(l0+l1), and
//    write final O directly to attn_out. 2 barriers/block total.
// Per-wave inner program byte-identical to attn8: reg-direct K/V fragments,
// V at iter top, K prefetch after S, lsum ones-MFMA, fixed-max exp2 softmax,
// permlane P-frag build.
// ---------------------------------------------------------------------------
__global__ __launch_bounds__(256, 2) void attn14(
    const bf16* __restrict__ qbuf, const bf16* __restrict__ kP,
    const bf16* __restrict__ vP, bf16* __restrict__ outO)
{
    __shared__ float ldsO[2][32][64];   // [rh][reg][lane] 16 KB
    __shared__ float ldsL[2][64];       // 512 B

    const int tid  = threadIdx.x;
    const int w    = tid >> 6;        // 0..3
    const int rh   = w & 1;           // q row-half
    const int s    = w >> 1;          // kv half
    const int lane = tid & 63;
    const int l31  = lane & 31;
    const int hh   = lane >> 5;       // K-half of the 32x32x16 fragment
    const int bid  = blockIdx.x;
    const int h    = bid & 15;
    const int bp   = bid >> 4;        // 0..31

    short8 ones8;
    #pragma unroll
    for (int i = 0; i < 8; ++i) ones8[i] = (short)0x3F80;

    #pragma unroll 1
    for (int pp = 0; pp < 2; ++pp) {
        const int tile = pp ? 63 - bp : bp;
        const int nIt  = tile + 1;
        const int mid  = (nIt + 1) >> 1;
        const int i0   = s ? mid : 0;
        const int iHi  = s ? nIt : mid;
        const int qw   = tile * 64 + rh * 32;
        const int q    = qw + l31;

        // Q fragments: B-operand Q[k=hd][col=q]; hd = ki*16 + hh*8 + j
        short8 qf[4];
        {
            const bf16* qp = qbuf + (size_t)q * CC + h * HD + hh * 8;
            #pragma unroll
            for (int ki = 0; ki < 4; ++ki)
                qf[ki] = *(const short8*)(qp + ki * 16);
        }

        f32x16 acc_l = {};       // lsum (rows identical per lane)
        f32x16 acc_o[2] = {};    // O^T: row d = dt*32 + (r&3)+8*(r>>2)+4*hh, col q=l31

        if (i0 < iHi) {
            const bf16* kb = kP + (size_t)h * 64 * AN + (size_t)i0 * 4096;
            const bf16* vb = vP + (size_t)h * 64 * AN + (size_t)i0 * 4096;
            const bool hasdiag = (iHi == nIt);

            // prologue: K(i0) direct to registers
            short8 kf[8];
            #pragma unroll
            for (int kt = 0; kt < 2; ++kt)
                #pragma unroll
                for (int ki = 0; ki < 4; ++ki)
                    kf[kt * 4 + ki] = *(const short8*)
                        (kb + (2 * ki + hh) * 512 + kt * 256 + l31 * 8);
            kb += 4096;

            for (int it = i0; it < iHi; ++it) {
                // ---- issue V(it) loads (consumed in PV, after S+softmax) ----
                short8 vf[8];
                #pragma unroll
                for (int kk = 0; kk < 4; ++kk)
                    #pragma unroll
                    for (int dt2 = 0; dt2 < 2; ++dt2)
                        vf[kk * 2 + dt2] = *(const short8*)
                            (vb + (2 * kk + hh) * 512 + dt2 * 256 + l31 * 8);
                vb += 4096;

                // ---- S^T = K.Q^T, two 32x32 kv-subtiles ----
                f32x16 st[2];
                __builtin_amdgcn_s_setprio(1);
                #pragma unroll
                for (int kt = 0; kt < 2; ++kt) {
                    f32x16 a = {};
                    #pragma unroll
                    for (int ki = 0; ki < 4; ++ki)
                        a = MFMA32(kf[kt * 4 + ki], qf[ki], a);
                    st[kt] = a;
                }
                __builtin_amdgcn_s_setprio(0);

                // ---- issue K(it+1) into kf (regs dead after S) ----
                if (it + 1 < iHi) {
                    #pragma unroll
                    for (int kt = 0; kt < 2; ++kt)
                        #pragma unroll
                        for (int ki = 0; ki < 4; ++ki)
                            kf[kt * 4 + ki] = *(const short8*)
                                (kb + (2 * ki + hh) * 512 + kt * 256 + l31 * 8);
                    kb += 4096;
                }

                // ---- fixed-max softmax: P = exp2(s), mask on diag tile ----
                if (hasdiag && it == iHi - 1) {
                    const int kv0 = it * 64;
                    #pragma unroll
                    for (int kt = 0; kt < 2; ++kt)
                        #pragma unroll
                        for (int r = 0; r < 16; ++r) {
                            const int kv = kv0 + kt * 32 + (r & 3) + 8 * (r >> 2) + 4 * hh;
                            st[kt][r] = (kv <= q) ? FAST_EXP2(st[kt][r]) : 0.0f;
                        }
                } else {
                    #pragma unroll
                    for (int kt = 0; kt < 2; ++kt)
                        #pragma unroll
                        for (int r = 0; r < 16; ++r)
                            st[kt][r] = FAST_EXP2(st[kt][r]);
                }

                // ---- P B-frags (cvt_pk + permlane32_swap), lsum-MFMA + PV ----
                #pragma unroll
                for (int kt = 0; kt < 2; ++kt)
                    #pragma unroll
                    for (int kc = 0; kc < 2; ++kc) {
                        unsigned a0 = pk2u(st[kt][kc * 8 + 0], st[kt][kc * 8 + 1]);
                        unsigned a1 = pk2u(st[kt][kc * 8 + 2], st[kt][kc * 8 + 3]);
                        unsigned c0 = pk2u(st[kt][kc * 8 + 4], st[kt][kc * 8 + 5]);
                        unsigned c1 = pk2u(st[kt][kc * 8 + 6], st[kt][kc * 8 + 7]);
                        plswap(a0, c0);
                        plswap(a1, c1);
                        uintv4 fu;
                        fu[0] = a0; fu[1] = a1; fu[2] = c0; fu[3] = c1;
                        const short8 frag = *(const short8*)&fu;

                        __builtin_amdgcn_s_setprio(1);
                        acc_l = MFMA32(ones8, frag, acc_l);
                        #pragma unroll
                        for (int dt2 = 0; dt2 < 2; ++dt2)
                            acc_o[dt2] = MFMA32(vf[(kt * 2 + kc) * 2 + dt2],
                                                frag, acc_o[dt2]);
                        __builtin_amdgcn_s_setprio(0);
                    }
            }
        }

        // ---- in-block combine: s=1 parks partials, s=0 merges & writes ----
        if (s == 1) {
            #pragma unroll
            for (int dt2 = 0; dt2 < 2; ++dt2)
                #pragma unroll
                for (int r = 0; r < 16; ++r)
                    ldsO[rh][dt2 * 16 + r][lane] = acc_o[dt2][r];
            ldsL[rh][lane] = acc_l[0];
        }
        __syncthreads();
        if (s == 0) {
            const float L = acc_l[0] + ldsL[rh][lane];
            const float invL = (L > 0.f) ? 1.f / L : 0.f;
            const size_t base = (size_t)q * CC + h * HD;
            #pragma unroll
            for (int dt2 = 0; dt2 < 2; ++dt2)
                #pragma unroll
                for (int g = 0; g < 4; ++g) {
                    const int d0 = dt2 * 32 + g * 8 + 4 * hh;
                    float o0 = (acc_o[dt2][4 * g + 0] + ldsO[rh][dt2 * 16 + 4 * g + 0][lane]) * invL;
                    float o1 = (acc_o[dt2][4 * g + 1] + ldsO[rh][dt2 * 16 + 4 * g + 1][lane]) * invL;
                    float o2 = (acc_o[dt2][4 * g + 2] + ldsO[rh][dt2 * 16 + 4 * g + 2][lane]) * invL;
                    float o3 = (acc_o[dt2][4 * g + 3] + ldsO[rh][dt2 * 16 + 4 * g + 3][lane]) * invL;
                    *(short4v*)&outO[base + d0] = pack4(o0, o1, o2, o3);
                }
        }
        __syncthreads();   // protect LDS reuse in next phase
    }
}

// ---------------------------------------------------------------------------
extern "C" void kernel_launch(void* const* d_in, const int* in_sizes, int n_in,
                              void* d_out, int out_size, void* d_ws, size_t ws_size,
                              hipStream_t stream) {
    char* ws = (char*)d_ws;
    bf16*   qbuf     = (bf16*)(ws);                    //  8 MiB [4096][1024]
    bf16*   kPack    = (bf16*)(ws + 8388608);          //  8 MiB frag-major K
    bf16*   vPack    = (bf16*)(ws + 16777216);         //  8 MiB frag-major V
    bf16*   attn_out = (bf16*)(ws + 25165824);         //  8 MiB [4096][1024]
    bf16*   xb       = (bf16*)(ws + 33554432);         //  8 MiB
    bf16*   wqkvb    = (bf16*)(ws + 41943040);         //  6 MiB
    bf16*   wprojb   = (bf16*)(ws + 48234496);         //  2 MiB
    float*  biasf    = (float*)(ws + 50331648);        //  4 KiB
    int*    mode     = (int*)(ws + 50335744);

    cast_all<<<dim3(4097), 256, 0, stream>>>(
        d_in[0], d_in[1], d_in[2], d_in[3], xb, wqkvb, wprojb, biasf, mode);

    // QKV projection: Q scaled -> qbuf; K -> kPack; V -> vPack (frag-major)
    gemm_qkv<<<dim3(C3 / BN, AN / BM), 256, 0, stream>>>(
        xb, wqkvb, qbuf, kPack, vPack);
    // causal flash attention: in-block kv-split combine, direct output
    attn14<<<dim3(32 * NH), 256, 0, stream>>>(qbuf, kPack, vPack, attn_out);
    // output projection + bias
    gemm_proj<<<dim3(CC / PN, AN / PM), 256, 0, stream>>>(
        attn_out, wprojb, biasf, d_out, mode);
}

// Round 10
// 185.106 us; speedup vs baseline: 1.3096x; 1.0055x over previous
//
#include <hip/hip_runtime.h>
#include <hip/hip_bf16.h>
#include <stdint.h>
#include <stddef.h>

using bf16 = __hip_bfloat16;
typedef short short8 __attribute__((ext_vector_type(8)));
typedef short short4v __attribute__((ext_vector_type(4)));
typedef short short2v __attribute__((ext_vector_type(2)));
typedef float f32x4 __attribute__((ext_vector_type(4)));
typedef float f32x16 __attribute__((ext_vector_type(16)));
typedef unsigned uintv4 __attribute__((ext_vector_type(4)));

#define MFMA16(A, B, C) __builtin_amdgcn_mfma_f32_16x16x32_bf16(A, B, C, 0, 0, 0)
#define MFMA32(A, B, C) __builtin_amdgcn_mfma_f32_32x32x16_bf16(A, B, C, 0, 0, 0)
#define GLOAD_LDS(g, l) __builtin_amdgcn_global_load_lds( \
    (const __attribute__((address_space(1))) void*)(g),   \
    (__attribute__((address_space(3))) void*)(l), 16, 0, 0)

// Problem constants
constexpr int AN  = 4096;   // sequence length N
constexpr int NH  = 16;     // heads
constexpr int HD  = 64;     // head dim
constexpr int CC  = 1024;   // channels = NH*HD
constexpr int C3  = 3072;   // 3*CC
// Q pre-scale: D^-0.5 * log2(e)  -> softmax runs in exp2 domain
constexpr float QSCALE = 0.125f * 1.4426950408889634f;

// ---- fast f32 -> bf16 (hardware cvt_pk if present, else bias+perm trick) ----
__device__ inline short bf16s(float f) {
    return (short)((__float_as_uint(f) + 0x8000u) >> 16);
}
__device__ inline float bf2f(short s) {
    return __uint_as_float(((unsigned)(unsigned short)s) << 16);
}
__device__ inline bf16 sbf(short s) {
    union { short s; bf16 b; } u;
    u.s = s;
    return u.b;
}
#if __has_builtin(__builtin_amdgcn_cvt_pk_bf16_f32)
typedef __bf16 bf16x2 __attribute__((ext_vector_type(2)));
__device__ inline short2v pk2(float a, float b) {
    bf16x2 r = __builtin_amdgcn_cvt_pk_bf16_f32(a, b);
    return *(short2v*)&r;
}
#else
__device__ inline short2v pk2(float a, float b) {   // 3 inst
    unsigned ua = __float_as_uint(a) + 0x8000u;
    unsigned ub = __float_as_uint(b) + 0x8000u;
    unsigned r  = __builtin_amdgcn_perm(ub, ua, 0x07060302);
    return *(short2v*)&r;
}
#endif
__device__ inline unsigned pk2u(float a, float b) {
    short2v p = pk2(a, b);
    return *(unsigned*)&p;
}
__device__ inline short4v pack4(float a, float b, float c, float d) {
    short2v lo = pk2(a, b), hi = pk2(c, d);
    short4v r;
    r[0] = lo[0]; r[1] = lo[1]; r[2] = hi[0]; r[3] = hi[1];
    return r;
}
// v_permlane32_swap_b32: upper 32 lanes of %0 exchange with lower 32 lanes
// of %1. After: a = [a_lo | b_lo(from lane-32)], b = [a_hi(from lane+32) | b_hi].
__device__ inline void plswap(unsigned &a, unsigned &b) {
    asm("v_permlane32_swap_b32 %0, %1" : "+v"(a), "+v"(b));
}
#if __has_builtin(__builtin_amdgcn_exp2f)
#define FAST_EXP2(x) __builtin_amdgcn_exp2f(x)
#else
#define FAST_EXP2(x) exp2f(x)
#endif

// ---------------------------------------------------------------------------
// Per-wave dtype detect (no extra kernel): every wave reads the same first
// 256 shorts of x; fp32-read-as-bf16 has ~45% wild exponents.
// ---------------------------------------------------------------------------
__device__ inline int detect_mode_inline(const unsigned short* xraw, int lane) {
    int crazy = 0;
    #pragma unroll
    for (int i = 0; i < 4; ++i) {
        const unsigned short u = xraw[lane * 4 + i];
        const int e = (u >> 7) & 0xFF;
        if (e >= 134 || (e != 0 && e <= 110)) ++crazy;
    }
    #pragma unroll
    for (int off = 32; off > 0; off >>= 1)
        crazy += __shfl_down(crazy, off, 64);
    crazy = __shfl(crazy, 0, 64);   // wave-uniform
    return (crazy >= 8) ? 1 : 0;
}

// ---------------------------------------------------------------------------
// One merged cast kernel: x (2048 blocks) | w_qkv (1536) | w_proj (512) |
// bias+mode (1 block). 8 elements/thread. Mode derived per-wave in-kernel.
// ---------------------------------------------------------------------------
__device__ inline void cast8(const void* __restrict__ src,
                             bf16* __restrict__ dst, int i, int m) {
    if (m) {
        const float* s = (const float*)src;
        float4 a = *(const float4*)(s + i);
        float4 b = *(const float4*)(s + i + 4);
        short8 o;
        short2v p0 = pk2(a.x, a.y), p1 = pk2(a.z, a.w);
        short2v p2 = pk2(b.x, b.y), p3 = pk2(b.z, b.w);
        o[0] = p0[0]; o[1] = p0[1]; o[2] = p1[0]; o[3] = p1[1];
        o[4] = p2[0]; o[5] = p2[1]; o[6] = p3[0]; o[7] = p3[1];
        *(short8*)(dst + i) = o;
    } else {
        *(short8*)(dst + i) = *(const short8*)((const short*)src + i);
    }
}

__global__ void cast_all(const void* __restrict__ x, const void* __restrict__ wq,
                         const void* __restrict__ wp, const void* __restrict__ bp,
                         bf16* __restrict__ xb, bf16* __restrict__ wqb,
                         bf16* __restrict__ wpb, float* __restrict__ biasf,
                         int* __restrict__ mode) {
    const int b = blockIdx.x;
    const int tid = threadIdx.x;
    const int m = detect_mode_inline((const unsigned short*)x, tid & 63);
    if (b < 2048) {
        cast8(x, xb, (b * 256 + tid) * 8, m);
    } else if (b < 3584) {
        cast8(wq, wqb, ((b - 2048) * 256 + tid) * 8, m);
    } else if (b < 4096) {
        cast8(wp, wpb, ((b - 3584) * 256 + tid) * 8, m);
    } else {
        #pragma unroll
        for (int i = tid; i < CC; i += 256)
            biasf[i] = m ? ((const float*)bp)[i] : bf2f(((const short*)bp)[i]);
        if (tid == 0) *mode = m;   // for gemm_proj's output dtype
    }
}

// ---------------------------------------------------------------------------
// QKV GEMM: Q cols scaled by QSCALE into qbuf[n][CC]; K cols written to
// fragment-major kPack[h][kvtile][dchunk(8)][row(64)][8]; V cols written to
// fragment-major vPack[h][kvtile][kvchunk(8)][d(64)][8].
// [Round-8 lesson: swapped-operand K epilogue = 188 MB writes; reverted.]
// 128x128 tile, BK=32, grid 24x32 = 768 = 3 blocks/CU exact fill.
// ---------------------------------------------------------------------------
constexpr int BM = 128, BN = 128, BK = 32;

__global__ __launch_bounds__(256, 3) void gemm_qkv(
    const bf16* __restrict__ A, const bf16* __restrict__ Bw,
    bf16* __restrict__ qOut, bf16* __restrict__ kOut, bf16* __restrict__ vOut)
{
    __shared__ bf16 As[BM * BK];
    __shared__ bf16 Bs[BN * BK];

    const int tid  = threadIdx.x;
    const int wave = tid >> 6;
    const int lane = tid & 63;
    const int quad = lane >> 4;
    const int l16  = lane & 15;
    const int wr   = wave >> 1;
    const int wc   = wave & 1;
    const int m0   = blockIdx.y * BM;
    const int o0   = blockIdx.x * BN;

    const int srow = lane >> 2;
    const int scol = (lane & 3) * 8;

    f32x4 acc[4][4] = {};

    for (int k0 = 0; k0 < CC; k0 += BK) {
        __syncthreads();
        #pragma unroll
        for (int c = 0; c < 2; ++c) {
            const int rbase = wave * 32 + c * 16;
            GLOAD_LDS(A + (size_t)(m0 + rbase + srow) * CC + k0 + scol, &As[rbase * BK]);
            GLOAD_LDS(Bw + (size_t)(o0 + rbase + srow) * CC + k0 + scol, &Bs[rbase * BK]);
        }
        __syncthreads();

        short8 af[4], bfr[4];
        #pragma unroll
        for (int i = 0; i < 4; ++i)
            af[i] = *(const short8*)&As[(wr * 64 + i * 16 + l16) * BK + quad * 8];
        #pragma unroll
        for (int j = 0; j < 4; ++j)
            bfr[j] = *(const short8*)&Bs[(wc * 64 + j * 16 + l16) * BK + quad * 8];
        #pragma unroll
        for (int i = 0; i < 4; ++i)
            #pragma unroll
            for (int j = 0; j < 4; ++j)
                acc[i][j] = MFMA16(af[i], bfr[j], acc[i][j]);
    }

    // epilogue: C/D layout col=l16, row=quad*4+reg
    if (o0 >= 2 * CC) {   // V block -> vPack[h][tile][kvchunk][d][8]
        #pragma unroll
        for (int j = 0; j < 4; ++j) {
            const int dcol = o0 - 2 * CC + wc * 64 + j * 16 + l16;
            const int hV = dcol >> 6, dV = dcol & 63;
            #pragma unroll
            for (int i = 0; i < 4; ++i) {
                const int kv0 = m0 + wr * 64 + i * 16 + quad * 4;
                const size_t addr = (size_t)hV * 64 * AN + (size_t)(kv0 >> 6) * 4096
                                  + (size_t)((kv0 >> 3) & 7) * 512 + dV * 8 + (kv0 & 7);
                *(short4v*)&vOut[addr] =
                    pack4(acc[i][j][0], acc[i][j][1], acc[i][j][2], acc[i][j][3]);
            }
        }
        return;
    }
    if (o0 >= CC) {       // K block -> kPack[h][tile][dchunk][row][8]
        #pragma unroll
        for (int j = 0; j < 4; ++j) {
            const int dcol = o0 - CC + wc * 64 + j * 16 + l16;
            const int hK = dcol >> 6, dc = (dcol >> 3) & 7, de = dcol & 7;
            #pragma unroll
            for (int i = 0; i < 4; ++i) {
                const int kv0 = m0 + wr * 64 + i * 16 + quad * 4;
                const size_t addr = (size_t)hK * 64 * AN + (size_t)(kv0 >> 6) * 4096
                                  + (size_t)dc * 512 + (size_t)(kv0 & 63) * 8 + de;
                #pragma unroll
                for (int r = 0; r < 4; ++r)
                    kOut[addr + r * 8] = sbf(bf16s(acc[i][j][r]));
            }
        }
        return;
    }
    // Q block -> qbuf[n][CC], scaled
    #pragma unroll
    for (int j = 0; j < 4; ++j) {
        const int col = o0 + wc * 64 + j * 16 + l16;
        #pragma unroll
        for (int i = 0; i < 4; ++i) {
            const int row = m0 + wr * 64 + i * 16 + quad * 4;
            #pragma unroll
            for (int r = 0; r < 2; ++r) {
                short2v p = pk2(acc[i][j][2 * r] * QSCALE, acc[i][j][2 * r + 1] * QSCALE);
                qOut[(size_t)(row + 2 * r) * CC + col]     = sbf(p[0]);
                qOut[(size_t)(row + 2 * r + 1) * CC + col] = sbf(p[1]);
            }
        }
    }
}

// ---------------------------------------------------------------------------
// Proj GEMM: out[m][o] = sum_c attn[m][c]*wp[o][c] + bias[o].
// 128x64 tile -> grid 16x32 = 512 = 2 blocks/CU exact fill.
// ---------------------------------------------------------------------------
constexpr int PM = 128, PN = 64, PK = 32;

__global__ __launch_bounds__(256, 2) void gemm_proj(
    const bf16* __restrict__ A, const bf16* __restrict__ Bw,
    const float* __restrict__ bias, void* __restrict__ Cout,
    const int* __restrict__ mode)
{
    __shared__ bf16 As[PM * PK];   // 8 KB
    __shared__ bf16 Bs[PN * PK];   // 4 KB

    const int tid  = threadIdx.x;
    const int wave = tid >> 6;
    const int lane = tid & 63;
    const int quad = lane >> 4;
    const int l16  = lane & 15;
    const int wr   = wave >> 1;
    const int wc   = wave & 1;
    const int m0   = blockIdx.y * PM;
    const int o0   = blockIdx.x * PN;
    const bool f32out = (*mode != 0);

    const int srow = lane >> 2;
    const int scol = (lane & 3) * 8;

    f32x4 acc[4][2] = {};

    for (int k0 = 0; k0 < CC; k0 += PK) {
        __syncthreads();
        #pragma unroll
        for (int c = 0; c < 2; ++c) {
            const int rbase = wave * 32 + c * 16;
            GLOAD_LDS(A + (size_t)(m0 + rbase + srow) * CC + k0 + scol, &As[rbase * PK]);
        }
        {
            const int rbase = wave * 16;
            GLOAD_LDS(Bw + (size_t)(o0 + rbase + srow) * CC + k0 + scol, &Bs[rbase * PK]);
        }
        __syncthreads();

        short8 af[4], bfr[2];
        #pragma unroll
        for (int i = 0; i < 4; ++i)
            af[i] = *(const short8*)&As[(wr * 64 + i * 16 + l16) * PK + quad * 8];
        #pragma unroll
        for (int j = 0; j < 2; ++j)
            bfr[j] = *(const short8*)&Bs[(wc * 32 + j * 16 + l16) * PK + quad * 8];
        #pragma unroll
        for (int i = 0; i < 4; ++i)
            #pragma unroll
            for (int j = 0; j < 2; ++j)
                acc[i][j] = MFMA16(af[i], bfr[j], acc[i][j]);
    }

    #pragma unroll
    for (int j = 0; j < 2; ++j) {
        const int col = o0 + wc * 32 + j * 16 + l16;
        const float bv = bias[col];
        #pragma unroll
        for (int i = 0; i < 4; ++i) {
            const int row = m0 + wr * 64 + i * 16 + quad * 4;
            if (f32out) {
                #pragma unroll
                for (int r = 0; r < 4; ++r)
                    ((float*)Cout)[(size_t)(row + r) * CC + col] = acc[i][j][r] + bv;
            } else {
                #pragma unroll
                for (int r = 0; r < 2; ++r) {
                    short2v p = pk2(acc[i][j][2 * r] + bv, acc[i][j][2 * r + 1] + bv);
                    ((bf16*)Cout)[(size_t)(row + 2 * r) * CC + col]     = sbf(p[0]);
                    ((bf16*)Cout)[(size_t)(row + 2 * r + 1) * CC + col] = sbf(p[1]);
                }
            }
        }
    }
}

// ---------------------------------------------------------------------------
// Causal flash attention v16: attn14's block structure + 2x reuse per load.
// Theory: per-CU L1 port (64 B/cy) is saturated — 8 waves x 16KB/iter for
// 32 q-rows each. Fix: each wave owns ALL 64 q-rows of the tile and a
// kv-QUARTER (s in 0..3): same 16KB/iter now serves 64 rows -> L1 demand
// halves. MFMA/iter = 32 (16 S + 16 PV; lsum-MFMA dropped -> VALU scalars,
// saving 32 AGPR — the register explosion that killed attn13's version).
//  - 512 blocks (h, bp), 4 waves = kv-quarters; pp phases (bp, 63-bp):
//    per-wave ~16.25 iters/phase, uniform across blocks.
//  - only wave s=3 sees the diagonal tile; (g0,kt1) there is fully masked
//    and skipped entirely.
//  - combine: 2-stage LDS tree (w1,w3 park; w0,w2 merge; w2 re-parks;
//    w0 finalizes + writes). 3 barriers/phase.
// Register budget ~233 total (2 waves/SIMD preserved; tripwire FETCH_SIZE).
// ---------------------------------------------------------------------------
__global__ __launch_bounds__(256, 2) void attn16(
    const bf16* __restrict__ qbuf, const bf16* __restrict__ kP,
    const bf16* __restrict__ vP, bf16* __restrict__ outO)
{
    __shared__ float ldsO[2][2][2][16][64];   // [slot][g][dt2][reg][lane] 32 KB
    __shared__ float ldsL[2][2][64];          // [slot][g][lane] 1 KB

    const int tid  = threadIdx.x;
    const int w    = tid >> 6;        // 0..3 = kv quarter
    const int lane = tid & 63;
    const int l31  = lane & 31;
    const int hh   = lane >> 5;       // K-half of the 32x32x16 fragment
    const int bid  = blockIdx.x;
    const int h    = bid & 15;
    const int bp   = bid >> 4;        // 0..31

    #pragma unroll 1
    for (int pp = 0; pp < 2; ++pp) {
        const int tile = pp ? 63 - bp : bp;
        const int nIt  = tile + 1;
        const int i0   = (nIt * w) >> 2;
        const int iHi  = (nIt * (w + 1)) >> 2;
        const int qb   = tile * 64;

        // Q fragments, both 32-row groups
        short8 qf[2][4];
        #pragma unroll
        for (int g = 0; g < 2; ++g) {
            const bf16* qp = qbuf + (size_t)(qb + 32 * g + l31) * CC + h * HD + hh * 8;
            #pragma unroll
            for (int ki = 0; ki < 4; ++ki)
                qf[g][ki] = *(const short8*)(qp + ki * 16);
        }

        float lsum[2] = {0.f, 0.f};
        f32x16 acc_o[2][2] = {};   // [g][dt2]

        if (i0 < iHi) {
            const bf16* kb = kP + (size_t)h * 64 * AN;
            const bf16* vb = vP + (size_t)h * 64 * AN;
            const bool hasdiag = (iHi == nIt);   // only wave 3

            // prologue: K(i0)
            short8 kf[8];
            #pragma unroll
            for (int kt = 0; kt < 2; ++kt)
                #pragma unroll
                for (int ki = 0; ki < 4; ++ki)
                    kf[kt * 4 + ki] = *(const short8*)
                        (kb + (size_t)i0 * 4096 + (2 * ki + hh) * 512 + kt * 256 + l31 * 8);

            for (int it = i0; it < iHi; ++it) {
                const bool diag = hasdiag && (it == iHi - 1);

                // ---- V(it) loads (consumed in PV, after S+softmax) ----
                short8 vf[4][2];
                {
                    const bf16* vs = vb + (size_t)it * 4096;
                    #pragma unroll
                    for (int kk = 0; kk < 4; ++kk)
                        #pragma unroll
                        for (int dt2 = 0; dt2 < 2; ++dt2)
                            vf[kk][dt2] = *(const short8*)
                                (vs + (2 * kk + hh) * 512 + dt2 * 256 + l31 * 8);
                }

                // ---- S + softmax + pack per (g,kt); st scoped (16 regs) ----
                short8 fr[2][4];   // [g][kt*2+kc]
                #pragma unroll
                for (int g = 0; g < 2; ++g) {
                    #pragma unroll
                    for (int kt = 0; kt < 2; ++kt) {
                        if (diag && g == 0 && kt == 1) continue; // fully masked
                        f32x16 st = {};
                        __builtin_amdgcn_s_setprio(1);
                        #pragma unroll
                        for (int ki = 0; ki < 4; ++ki)
                            st = MFMA32(kf[kt * 4 + ki], qf[g][ki], st);
                        __builtin_amdgcn_s_setprio(0);

                        // mask+exp2: tri iff diag tile and this (g,kt) hits it
                        const bool tri = diag && ((g == 0 && kt == 0) ||
                                                  (g == 1 && kt == 1));
                        const int qrel = g * 32 + l31;
                        if (tri) {
                            #pragma unroll
                            for (int r = 0; r < 16; ++r) {
                                const int kv = kt * 32 + (r & 3) + 8 * (r >> 2) + 4 * hh;
                                st[r] = (kv <= qrel) ? FAST_EXP2(st[r]) : 0.0f;
                            }
                        } else {
                            #pragma unroll
                            for (int r = 0; r < 16; ++r)
                                st[r] = FAST_EXP2(st[r]);
                        }

                        // lsum partials (VALU; 4 chains)
                        {
                            float s0 = 0.f, s1 = 0.f, s2 = 0.f, s3 = 0.f;
                            #pragma unroll
                            for (int r = 0; r < 16; r += 4) {
                                s0 += st[r];     s1 += st[r + 1];
                                s2 += st[r + 2]; s3 += st[r + 3];
                            }
                            lsum[g] += (s0 + s1) + (s2 + s3);
                        }

                        // pack to PV B-frags
                        #pragma unroll
                        for (int kc = 0; kc < 2; ++kc) {
                            unsigned a0 = pk2u(st[kc * 8 + 0], st[kc * 8 + 1]);
                            unsigned a1 = pk2u(st[kc * 8 + 2], st[kc * 8 + 3]);
                            unsigned c0 = pk2u(st[kc * 8 + 4], st[kc * 8 + 5]);
                            unsigned c1 = pk2u(st[kc * 8 + 6], st[kc * 8 + 7]);
                            plswap(a0, c0);
                            plswap(a1, c1);
                            uintv4 fu;
                            fu[0] = a0; fu[1] = a1; fu[2] = c0; fu[3] = c1;
                            fr[g][kt * 2 + kc] = *(const short8*)&fu;
                        }
                    }
                }

                // ---- K(it+1) prefetch (kf dead after both groups' S) ----
                if (it + 1 < iHi) {
                    #pragma unroll
                    for (int kt = 0; kt < 2; ++kt)
                        #pragma unroll
                        for (int ki = 0; ki < 4; ++ki)
                            kf[kt * 4 + ki] = *(const short8*)
                                (kb + (size_t)(it + 1) * 4096
                                 + (2 * ki + hh) * 512 + kt * 256 + l31 * 8);
                }

                // ---- PV, both groups (skip masked g0/kt1 at diag) ----
                __builtin_amdgcn_s_setprio(1);
                #pragma unroll
                for (int g = 0; g < 2; ++g)
                    #pragma unroll
                    for (int kt = 0; kt < 2; ++kt) {
                        if (diag && g == 0 && kt == 1) continue;
                        #pragma unroll
                        for (int kc = 0; kc < 2; ++kc)
                            #pragma unroll
                            for (int dt2 = 0; dt2 < 2; ++dt2)
                                acc_o[g][dt2] = MFMA32(vf[kt * 2 + kc][dt2],
                                                       fr[g][kt * 2 + kc],
                                                       acc_o[g][dt2]);
                    }
                __builtin_amdgcn_s_setprio(0);
            }
        }

        // ---- cross-hh lsum (kv split across hh pair) ----
        float lt[2];
        #pragma unroll
        for (int g = 0; g < 2; ++g)
            lt[g] = lsum[g] + __shfl_xor(lsum[g], 32, 64);

        // ---- 2-stage in-block combine of the 4 kv-quarter partials ----
        // stage 1: w1 -> slot0, w3 -> slot1
        if (w == 1 || w == 3) {
            const int slot = w >> 1;
            #pragma unroll
            for (int g = 0; g < 2; ++g) {
                #pragma unroll
                for (int dt2 = 0; dt2 < 2; ++dt2)
                    #pragma unroll
                    for (int r = 0; r < 16; ++r)
                        ldsO[slot][g][dt2][r][lane] = acc_o[g][dt2][r];
                ldsL[slot][g][lane] = lt[g];
            }
        }
        __syncthreads();
        if (w == 0 || w == 2) {
            const int slot = w >> 1;
            #pragma unroll
            for (int g = 0; g < 2; ++g) {
                #pragma unroll
                for (int dt2 = 0; dt2 < 2; ++dt2)
                    #pragma unroll
                    for (int r = 0; r < 16; ++r)
                        acc_o[g][dt2][r] += ldsO[slot][g][dt2][r][lane];
                lt[g] += ldsL[slot][g][lane];
            }
        }
        // stage 2: w2 re-parks its merged half into slot1
        if (w == 2) {
            #pragma unroll
            for (int g = 0; g < 2; ++g) {
                #pragma unroll
                for (int dt2 = 0; dt2 < 2; ++dt2)
                    #pragma unroll
                    for (int r = 0; r < 16; ++r)
                        ldsO[1][g][dt2][r][lane] = acc_o[g][dt2][r];
                ldsL[1][g][lane] = lt[g];
            }
        }
        __syncthreads();
        if (w == 0) {
            #pragma unroll
            for (int g = 0; g < 2; ++g) {
                #pragma unroll
                for (int dt2 = 0; dt2 < 2; ++dt2)
                    #pragma unroll
                    for (int r = 0; r < 16; ++r)
                        acc_o[g][dt2][r] += ldsO[1][g][dt2][r][lane];
                const float L = lt[g] + ldsL[1][g][lane];
                const float invL = (L > 0.f) ? 1.f / L : 0.f;
                const size_t base = (size_t)(qb + 32 * g + l31) * CC + h * HD;
                #pragma unroll
                for (int dt2 = 0; dt2 < 2; ++dt2)
                    #pragma unroll
                    for (int gi = 0; gi < 4; ++gi) {
                        const int d0 = dt2 * 32 + gi * 8 + 4 * hh;
                        *(short4v*)&outO[base + d0] = pack4(
                            acc_o[g][dt2][4 * gi + 0] * invL,
                            acc_o[g][dt2][4 * gi + 1] * invL,
                            acc_o[g][dt2][4 * gi + 2] * invL,
                            acc_o[g][dt2][4 * gi + 3] * invL);
                    }
            }
        }
        __syncthreads();   // protect LDS reuse in next phase
    }
}

// ---------------------------------------------------------------------------
extern "C" void kernel_launch(void* const* d_in, const int* in_sizes, int n_in,
                              void* d_out, int out_size, void* d_ws, size_t ws_size,
                              hipStream_t stream) {
    char* ws = (char*)d_ws;
    bf16*   qbuf     = (bf16*)(ws);                    //  8 MiB [4096][1024]
    bf16*   kPack    = (bf16*)(ws + 8388608);          //  8 MiB frag-major K
    bf16*   vPack    = (bf16*)(ws + 16777216);         //  8 MiB frag-major V
    bf16*   attn_out = (bf16*)(ws + 25165824);         //  8 MiB [4096][1024]
    bf16*   xb       = (bf16*)(ws + 33554432);         //  8 MiB
    bf16*   wqkvb    = (bf16*)(ws + 41943040);         //  6 MiB
    bf16*   wprojb   = (bf16*)(ws + 48234496);         //  2 MiB
    float*  biasf    = (float*)(ws + 50331648);        //  4 KiB
    int*    mode     = (int*)(ws + 50335744);

    cast_all<<<dim3(4097), 256, 0, stream>>>(
        d_in[0], d_in[1], d_in[2], d_in[3], xb, wqkvb, wprojb, biasf, mode);

    // QKV projection: Q scaled -> qbuf; K -> kPack; V -> vPack (frag-major)
    gemm_qkv<<<dim3(C3 / BN, AN / BM), 256, 0, stream>>>(
        xb, wqkvb, qbuf, kPack, vPack);
    // causal flash attention: 64 q-rows/wave, kv-quarter waves, in-block combine
    attn16<<<dim3(32 * NH), 256, 0, stream>>>(qbuf, kPack, vPack, attn_out);
    // output projection + bias
    gemm_proj<<<dim3(CC / PN, AN / PM), 256, 0, stream>>>(
        attn_out, wprojb, biasf, d_out, mode);
}